// Round 12
// baseline (47.125 us; speedup 1.0000x reference)
//
#include <hip/hip_runtime.h>

#define DD 2048
#define MHH 32

typedef _Float16 hf2 __attribute__((ext_vector_type(2)));

__device__ __forceinline__ unsigned pack_pair(float lo, float hi) {
    hf2 v;
    v.x = (_Float16)lo;
    v.y = (_Float16)hi;
    return __builtin_bit_cast(unsigned, v);
}

__device__ __forceinline__ hf2 rfl2(unsigned u) {
    u = __builtin_amdgcn_readfirstlane(u);     // force SGPR residency
    return __builtin_bit_cast(hf2, u);
}

__device__ __forceinline__ hf2 dup16(float x) {
    hf2 v;
    v.x = (_Float16)x;
    v.y = v.x;
    return v;
}

// ---- gemv: 4 rows per block (one wave per row), y = relu(W x + b) ----
__device__ __forceinline__ void gemv4_body(const float* __restrict__ W,
                                           const float* __restrict__ x,
                                           const float* __restrict__ b,
                                           float* __restrict__ y, int blk) {
    const int wave = threadIdx.x >> 6;
    const int lane = threadIdx.x & 63;
    const int row  = (blk << 2) + wave;
    const float* Wr = W + (size_t)row * DD;
    float acc = 0.f;
#pragma unroll
    for (int it = 0; it < 8; ++it) {
        const int col = ((it << 6) + lane) << 2;       // float4 index, coalesced
        const float4 w4 = *reinterpret_cast<const float4*>(Wr + col);
        const float4 x4 = *reinterpret_cast<const float4*>(x + col);
        acc = fmaf(w4.x, x4.x, acc);
        acc = fmaf(w4.y, x4.y, acc);
        acc = fmaf(w4.z, x4.z, acc);
        acc = fmaf(w4.w, x4.w, acc);
    }
#pragma unroll
    for (int off = 32; off > 0; off >>= 1)
        acc += __shfl_down(acc, off, 64);
    if (lane == 0) {
        const float v = acc + b[row];
        y[row] = fmaxf(v, 0.f);
    }
}

// k1: gemv layer1 (blocks 0..511) + constant-packing block (block 512).
__global__ __launch_bounds__(256) void gemv_relu_prep_k(const float* __restrict__ W,
                                                        const float* __restrict__ x,
                                                        const float* __restrict__ b,
                                                        float* __restrict__ y,
                                                        const float* __restrict__ Wm1,
                                                        const float* __restrict__ bm1,
                                                        const float* __restrict__ Wm2,
                                                        unsigned* __restrict__ cst) {
    if (blockIdx.x == DD / 4) {
        const int mp = threadIdx.x;
        if (mp < MHH / 2) {
            const int m = 2 * mp;
            cst[mp]      = pack_pair(Wm1[m],           Wm1[m + 1]);            // A
            cst[16 + mp] = pack_pair(Wm1[MHH + m],     Wm1[MHH + m + 1]);      // B
            cst[32 + mp] = pack_pair(Wm2[m],           Wm2[m + 1]);            // V2
            cst[48 + mp] = pack_pair(Wm1[2 * MHH + m], Wm1[2 * MHH + m + 1]);  // C
            cst[64 + mp] = pack_pair(bm1[m],           bm1[m + 1]);            // bm1
        }
        return;
    }
    gemv4_body(W, x, b, y, blockIdx.x);
}

__global__ __launch_bounds__(256) void gemv_relu_k(const float* __restrict__ W,
                                                   const float* __restrict__ x,
                                                   const float* __restrict__ b,
                                                   float* __restrict__ y) {
    gemv4_body(W, x, b, y, blockIdx.x);
}

// meta: 1536 blocks (512 per layer), each block = FOUR consecutive rows.
// Depth-1 prefetch: row r+1's W float4s are loaded (and converted to f16
// dups) BEFORE row r's inner loop, so HBM/L3 latency hides under the
// 512-instruction compute phase. Only row 0's load latency is exposed.
__global__ __launch_bounds__(256, 6) void meta_k(const float* __restrict__ W1,
                                                 const float* __restrict__ W2,
                                                 const float* __restrict__ W3,
                                                 const float* __restrict__ a0,
                                                 const float* __restrict__ a1,
                                                 const float* __restrict__ a2,
                                                 const float* __restrict__ a3,
                                                 const unsigned* __restrict__ cst,
                                                 const float* __restrict__ bm2,
                                                 float* __restrict__ nW) {
    const int layer = blockIdx.x >> 9;           // 512 blocks per layer
    const int row0  = (blockIdx.x & 511) << 2;   // 4 consecutive rows

    const float* W   = (layer == 0) ? W1 : (layer == 1) ? W2 : W3;
    const float* inp = (layer == 0) ? a0 : (layer == 1) ? a1 : a2;
    const float* oup = (layer == 0) ? a1 : (layer == 1) ? a2 : a3;

    const float* Wr  = W  + (size_t)row0 * DD;
    float*       nWr = nW + (size_t)layer * DD * DD + (size_t)row0 * DD;

    const int col0 = threadIdx.x * 4;            // first half, coalesced float4
    const int col1 = (DD / 2) + threadIdx.x * 4; // second half

    // Shared (per-block) loads: input vector halves + the 4 output activations.
    const float4 u4a = *reinterpret_cast<const float4*>(inp + col0);
    const float4 u4b = *reinterpret_cast<const float4*>(inp + col1);
    const float4 ov4 = *reinterpret_cast<const float4*>(oup + row0);

    // Row-0 W loads issued as early as possible.
    float4 wfa = *reinterpret_cast<const float4*>(Wr + col0);
    float4 wfb = *reinterpret_cast<const float4*>(Wr + col1);

    // ---- constants: A/B/V2/C -> SGPR, bm1 -> VGPR (once per block) ----
    const uint4* c16 = (const uint4*)cst;
    hf2 Ap[MHH / 2], Bp[MHH / 2], Vp[MHH / 2], Cm[MHH / 2], Bm[MHH / 2];
#pragma unroll
    for (int j = 0; j < 4; ++j) {
        const uint4 t = c16[j];
        Ap[4 * j + 0] = rfl2(t.x); Ap[4 * j + 1] = rfl2(t.y);
        Ap[4 * j + 2] = rfl2(t.z); Ap[4 * j + 3] = rfl2(t.w);
    }
#pragma unroll
    for (int j = 0; j < 4; ++j) {
        const uint4 t = c16[4 + j];
        Bp[4 * j + 0] = rfl2(t.x); Bp[4 * j + 1] = rfl2(t.y);
        Bp[4 * j + 2] = rfl2(t.z); Bp[4 * j + 3] = rfl2(t.w);
    }
#pragma unroll
    for (int j = 0; j < 4; ++j) {
        const uint4 t = c16[8 + j];
        Vp[4 * j + 0] = rfl2(t.x); Vp[4 * j + 1] = rfl2(t.y);
        Vp[4 * j + 2] = rfl2(t.z); Vp[4 * j + 3] = rfl2(t.w);
    }
#pragma unroll
    for (int j = 0; j < 4; ++j) {
        const uint4 tc = c16[12 + j];
        const uint4 tb = c16[16 + j];
        Cm[4 * j + 0] = rfl2(tc.x); Cm[4 * j + 1] = rfl2(tc.y);
        Cm[4 * j + 2] = rfl2(tc.z); Cm[4 * j + 3] = rfl2(tc.w);
        Bm[4 * j + 0] = __builtin_bit_cast(hf2, tb.x);
        Bm[4 * j + 1] = __builtin_bit_cast(hf2, tb.y);
        Bm[4 * j + 2] = __builtin_bit_cast(hf2, tb.z);
        Bm[4 * j + 3] = __builtin_bit_cast(hf2, tb.w);
    }
    const float bias2 = bm2[0];

    // Shared input dups (pinned — invariant across all 4 rows and the m-loop).
    hf2 ud[8];
    ud[0] = dup16(u4a.x); ud[1] = dup16(u4a.y); ud[2] = dup16(u4a.z); ud[3] = dup16(u4a.w);
    ud[4] = dup16(u4b.x); ud[5] = dup16(u4b.y); ud[6] = dup16(u4b.z); ud[7] = dup16(u4b.w);
    asm volatile("" : "+v"(ud[0]), "+v"(ud[1]), "+v"(ud[2]), "+v"(ud[3]),
                      "+v"(ud[4]), "+v"(ud[5]), "+v"(ud[6]), "+v"(ud[7]));

    const hf2 zero = (hf2)(_Float16)0.f;

#pragma unroll
    for (int r = 0; r < 4; ++r) {
        // Convert current row's W to f16 dups (pinned).
        hf2 wd[8];
        wd[0] = dup16(wfa.x); wd[1] = dup16(wfa.y); wd[2] = dup16(wfa.z); wd[3] = dup16(wfa.w);
        wd[4] = dup16(wfb.x); wd[5] = dup16(wfb.y); wd[6] = dup16(wfb.z); wd[7] = dup16(wfb.w);
        asm volatile("" : "+v"(wd[0]), "+v"(wd[1]), "+v"(wd[2]), "+v"(wd[3]),
                          "+v"(wd[4]), "+v"(wd[5]), "+v"(wd[6]), "+v"(wd[7]));

        // PREFETCH next row's W — issued before the 512-instr inner loop so
        // the load latency hides under row r's compute.
        if (r < 3) {
            const float* Wn = Wr + (size_t)(r + 1) * DD;
            wfa = *reinterpret_cast<const float4*>(Wn + col0);
            wfb = *reinterpret_cast<const float4*>(Wn + col1);
        }

        const float ovr = (r == 0) ? ov4.x : (r == 1) ? ov4.y : (r == 2) ? ov4.z : ov4.w;
        const hf2 ovd = dup16(ovr);
        hf2 Pp[MHH / 2];
#pragma unroll
        for (int mp = 0; mp < MHH / 2; ++mp) {
            Pp[mp] = __builtin_elementwise_fma(ovd, Cm[mp], Bm[mp]);
            asm volatile("" : "+v"(Pp[mp]));    // keep P in VGPR
        }

        float c0 = bias2, c1 = bias2, c2 = bias2, c3 = bias2;
        float c4 = bias2, c5 = bias2, c6 = bias2, c7 = bias2;

#pragma unroll
        for (int mp = 0; mp < MHH / 2; ++mp) {
            const hf2 a = Ap[mp], b = Bp[mp], v = Vp[mp], p = Pp[mp];
            hf2 q0 = __builtin_elementwise_fma(ud[0], a, p);
            hf2 q1 = __builtin_elementwise_fma(ud[1], a, p);
            hf2 q2 = __builtin_elementwise_fma(ud[2], a, p);
            hf2 q3 = __builtin_elementwise_fma(ud[3], a, p);
            hf2 q4 = __builtin_elementwise_fma(ud[4], a, p);
            hf2 q5 = __builtin_elementwise_fma(ud[5], a, p);
            hf2 q6 = __builtin_elementwise_fma(ud[6], a, p);
            hf2 q7 = __builtin_elementwise_fma(ud[7], a, p);
            q0 = __builtin_elementwise_fma(wd[0], b, q0);
            q1 = __builtin_elementwise_fma(wd[1], b, q1);
            q2 = __builtin_elementwise_fma(wd[2], b, q2);
            q3 = __builtin_elementwise_fma(wd[3], b, q3);
            q4 = __builtin_elementwise_fma(wd[4], b, q4);
            q5 = __builtin_elementwise_fma(wd[5], b, q5);
            q6 = __builtin_elementwise_fma(wd[6], b, q6);
            q7 = __builtin_elementwise_fma(wd[7], b, q7);
            q0 = __builtin_elementwise_max(q0, zero);
            q1 = __builtin_elementwise_max(q1, zero);
            q2 = __builtin_elementwise_max(q2, zero);
            q3 = __builtin_elementwise_max(q3, zero);
            q4 = __builtin_elementwise_max(q4, zero);
            q5 = __builtin_elementwise_max(q5, zero);
            q6 = __builtin_elementwise_max(q6, zero);
            q7 = __builtin_elementwise_max(q7, zero);
            c0 = __builtin_amdgcn_fdot2(q0, v, c0, false);
            c1 = __builtin_amdgcn_fdot2(q1, v, c1, false);
            c2 = __builtin_amdgcn_fdot2(q2, v, c2, false);
            c3 = __builtin_amdgcn_fdot2(q3, v, c3, false);
            c4 = __builtin_amdgcn_fdot2(q4, v, c4, false);
            c5 = __builtin_amdgcn_fdot2(q5, v, c5, false);
            c6 = __builtin_amdgcn_fdot2(q6, v, c6, false);
            c7 = __builtin_amdgcn_fdot2(q7, v, c7, false);
        }

        float4 r0, r1;
        r0.x = c0; r0.y = c1; r0.z = c2; r0.w = c3;
        r1.x = c4; r1.y = c5; r1.z = c6; r1.w = c7;
        float* nWrr = nWr + (size_t)r * DD;
        *reinterpret_cast<float4*>(nWrr + col0) = r0;
        *reinterpret_cast<float4*>(nWrr + col1) = r1;
    }
}

extern "C" void kernel_launch(void* const* d_in, const int* in_sizes, int n_in,
                              void* d_out, int out_size, void* d_ws, size_t ws_size,
                              hipStream_t stream) {
    const float* x   = (const float*)d_in[0];
    const float* W1  = (const float*)d_in[1];
    const float* b1  = (const float*)d_in[2];
    const float* W2  = (const float*)d_in[3];
    const float* b2  = (const float*)d_in[4];
    const float* W3  = (const float*)d_in[5];
    const float* b3  = (const float*)d_in[6];
    const float* Wm1 = (const float*)d_in[7];
    const float* bm1 = (const float*)d_in[8];
    const float* Wm2 = (const float*)d_in[9];
    const float* bm2 = (const float*)d_in[10];

    float* out = (float*)d_out;            // out: [2048]
    float* nW  = out + DD;                 // nW1|nW2|nW3: 3 x 2048 x 2048
    float* a1  = (float*)d_ws;             // [2048]
    float* a2  = a1 + DD;                  // [2048]
    unsigned* cst = (unsigned*)(a2 + DD);  // [80] packed f16x2 constants

    gemv_relu_prep_k<<<DD / 4 + 1, 256, 0, stream>>>(W1, x, b1, a1, Wm1, bm1, Wm2, cst);
    gemv_relu_k<<<DD / 4, 256, 0, stream>>>(W2, a1, b2, a2);
    gemv_relu_k<<<DD / 4, 256, 0, stream>>>(W3, a2, b3, out);
    meta_k<<<3 * DD / 4, 256, 0, stream>>>(W1, W2, W3, x, a1, a2, out,
                                           cst, bm2, nW);
}

// Round 13
// 46.659 us; speedup vs baseline: 1.0100x; 1.0100x over previous
//
#include <hip/hip_runtime.h>

#define DD 2048
#define MHH 32

typedef _Float16 hf2 __attribute__((ext_vector_type(2)));

__device__ __forceinline__ unsigned pack_pair(float lo, float hi) {
    hf2 v;
    v.x = (_Float16)lo;
    v.y = (_Float16)hi;
    return __builtin_bit_cast(unsigned, v);
}

__device__ __forceinline__ hf2 rfl2(unsigned u) {
    u = __builtin_amdgcn_readfirstlane(u);     // force SGPR residency
    return __builtin_bit_cast(hf2, u);
}

__device__ __forceinline__ hf2 dup16(float x) {
    hf2 v;
    v.x = (_Float16)x;
    v.y = v.x;
    return v;
}

// ---- gemv: 4 rows per block (one wave per row), y = relu(W x + b) ----
__device__ __forceinline__ void gemv4_body(const float* __restrict__ W,
                                           const float* __restrict__ x,
                                           const float* __restrict__ b,
                                           float* __restrict__ y, int blk) {
    const int wave = threadIdx.x >> 6;
    const int lane = threadIdx.x & 63;
    const int row  = (blk << 2) + wave;
    const float* Wr = W + (size_t)row * DD;
    float acc = 0.f;
#pragma unroll
    for (int it = 0; it < 8; ++it) {
        const int col = ((it << 6) + lane) << 2;       // float4 index, coalesced
        const float4 w4 = *reinterpret_cast<const float4*>(Wr + col);
        const float4 x4 = *reinterpret_cast<const float4*>(x + col);
        acc = fmaf(w4.x, x4.x, acc);
        acc = fmaf(w4.y, x4.y, acc);
        acc = fmaf(w4.z, x4.z, acc);
        acc = fmaf(w4.w, x4.w, acc);
    }
#pragma unroll
    for (int off = 32; off > 0; off >>= 1)
        acc += __shfl_down(acc, off, 64);
    if (lane == 0) {
        const float v = acc + b[row];
        y[row] = fmaxf(v, 0.f);
    }
}

// k1: gemv layer1 (blocks 0..511) + constant-packing block (block 512).
__global__ __launch_bounds__(256) void gemv_relu_prep_k(const float* __restrict__ W,
                                                        const float* __restrict__ x,
                                                        const float* __restrict__ b,
                                                        float* __restrict__ y,
                                                        const float* __restrict__ Wm1,
                                                        const float* __restrict__ bm1,
                                                        const float* __restrict__ Wm2,
                                                        unsigned* __restrict__ cst) {
    if (blockIdx.x == DD / 4) {
        const int mp = threadIdx.x;
        if (mp < MHH / 2) {
            const int m = 2 * mp;
            cst[mp]      = pack_pair(Wm1[m],           Wm1[m + 1]);            // A
            cst[16 + mp] = pack_pair(Wm1[MHH + m],     Wm1[MHH + m + 1]);      // B
            cst[32 + mp] = pack_pair(Wm2[m],           Wm2[m + 1]);            // V2
            cst[48 + mp] = pack_pair(Wm1[2 * MHH + m], Wm1[2 * MHH + m + 1]);  // C
            cst[64 + mp] = pack_pair(bm1[m],           bm1[m + 1]);            // bm1
        }
        return;
    }
    gemv4_body(W, x, b, y, blockIdx.x);
}

__global__ __launch_bounds__(256) void gemv_relu_k(const float* __restrict__ W,
                                                   const float* __restrict__ x,
                                                   const float* __restrict__ b,
                                                   float* __restrict__ y) {
    gemv4_body(W, x, b, y, blockIdx.x);
}

// meta: 768 blocks (256 per layer), 512 threads, EIGHT rows per block,
// 4 elements per thread. P pairs (bm1 + ov*C, f16) are computed once per
// block by threads 0..127 into LDS and broadcast-read per row
// (uniform-address ds_read_b128 -> conflict-free). Inner loop unchanged:
// 4 packed VALU ops per (element, m-pair), f32 accumulate via dot2.
__global__ __launch_bounds__(512, 6) void meta_k(const float* __restrict__ W1,
                                                 const float* __restrict__ W2,
                                                 const float* __restrict__ W3,
                                                 const float* __restrict__ a0,
                                                 const float* __restrict__ a1,
                                                 const float* __restrict__ a2,
                                                 const float* __restrict__ a3,
                                                 const unsigned* __restrict__ cst,
                                                 const float* __restrict__ bm2,
                                                 float* __restrict__ nW) {
    const int layer = blockIdx.x >> 8;           // 256 blocks per layer
    const int row0  = (blockIdx.x & 255) << 3;   // 8 consecutive rows

    const float* W   = (layer == 0) ? W1 : (layer == 1) ? W2 : W3;
    const float* inp = (layer == 0) ? a0 : (layer == 1) ? a1 : a2;
    const float* oup = (layer == 0) ? a1 : (layer == 1) ? a2 : a3;

    const float* Wr  = W  + (size_t)row0 * DD;
    float*       nWr = nW + (size_t)layer * DD * DD + (size_t)row0 * DD;

    const int col = threadIdx.x * 4;             // 4 elements/thread, coalesced

    // Shared input chunk (one float4 per thread covers the whole row).
    const float4 u4 = *reinterpret_cast<const float4*>(inp + col);

    // ---- P pairs into LDS: threads 0..127, one (row, m-pair) each ----
    __shared__ __align__(16) unsigned Plds[8 * 16];
    if (threadIdx.x < 128) {
        const int r  = threadIdx.x >> 4;
        const int mp = threadIdx.x & 15;
        const hf2 ovd = dup16(oup[row0 + r]);
        const hf2 Cv  = __builtin_bit_cast(hf2, cst[48 + mp]);
        const hf2 Bv  = __builtin_bit_cast(hf2, cst[64 + mp]);
        const hf2 p   = __builtin_elementwise_fma(ovd, Cv, Bv);
        Plds[r * 16 + mp] = __builtin_bit_cast(unsigned, p);
    }

    // ---- constants: A/B/V2 -> SGPR ----
    const uint4* c16 = (const uint4*)cst;
    hf2 Ap[MHH / 2], Bp[MHH / 2], Vp[MHH / 2];
#pragma unroll
    for (int j = 0; j < 4; ++j) {
        const uint4 t = c16[j];
        Ap[4 * j + 0] = rfl2(t.x); Ap[4 * j + 1] = rfl2(t.y);
        Ap[4 * j + 2] = rfl2(t.z); Ap[4 * j + 3] = rfl2(t.w);
    }
#pragma unroll
    for (int j = 0; j < 4; ++j) {
        const uint4 t = c16[4 + j];
        Bp[4 * j + 0] = rfl2(t.x); Bp[4 * j + 1] = rfl2(t.y);
        Bp[4 * j + 2] = rfl2(t.z); Bp[4 * j + 3] = rfl2(t.w);
    }
#pragma unroll
    for (int j = 0; j < 4; ++j) {
        const uint4 t = c16[8 + j];
        Vp[4 * j + 0] = rfl2(t.x); Vp[4 * j + 1] = rfl2(t.y);
        Vp[4 * j + 2] = rfl2(t.z); Vp[4 * j + 3] = rfl2(t.w);
    }
    const float bias2 = bm2[0];

    // Input dups (pinned — invariant across all 8 rows and the m-loop).
    hf2 ud[4];
    ud[0] = dup16(u4.x); ud[1] = dup16(u4.y); ud[2] = dup16(u4.z); ud[3] = dup16(u4.w);
    asm volatile("" : "+v"(ud[0]), "+v"(ud[1]), "+v"(ud[2]), "+v"(ud[3]));

    const hf2 zero = (hf2)(_Float16)0.f;

    __syncthreads();                             // P ready in LDS

#pragma unroll
    for (int r = 0; r < 8; ++r) {
        const float* Wrr = Wr + (size_t)r * DD;
        const float4 wa = *reinterpret_cast<const float4*>(Wrr + col);

        // Row's P pairs: 4 uniform-address b128 reads (broadcast).
        const uint4* pl = (const uint4*)&Plds[r * 16];
        hf2 Pp[16];
#pragma unroll
        for (int j = 0; j < 4; ++j) {
            const uint4 t = pl[j];
            Pp[4 * j + 0] = __builtin_bit_cast(hf2, t.x);
            Pp[4 * j + 1] = __builtin_bit_cast(hf2, t.y);
            Pp[4 * j + 2] = __builtin_bit_cast(hf2, t.z);
            Pp[4 * j + 3] = __builtin_bit_cast(hf2, t.w);
            asm volatile("" : "+v"(Pp[4 * j + 0]), "+v"(Pp[4 * j + 1]),
                              "+v"(Pp[4 * j + 2]), "+v"(Pp[4 * j + 3]));
        }

        hf2 wd[4];
        wd[0] = dup16(wa.x); wd[1] = dup16(wa.y); wd[2] = dup16(wa.z); wd[3] = dup16(wa.w);
        asm volatile("" : "+v"(wd[0]), "+v"(wd[1]), "+v"(wd[2]), "+v"(wd[3]));

        float c0 = bias2, c1 = bias2, c2 = bias2, c3 = bias2;

#pragma unroll
        for (int mp = 0; mp < MHH / 2; ++mp) {
            const hf2 a = Ap[mp], b = Bp[mp], v = Vp[mp], p = Pp[mp];
            hf2 q0 = __builtin_elementwise_fma(ud[0], a, p);
            hf2 q1 = __builtin_elementwise_fma(ud[1], a, p);
            hf2 q2 = __builtin_elementwise_fma(ud[2], a, p);
            hf2 q3 = __builtin_elementwise_fma(ud[3], a, p);
            q0 = __builtin_elementwise_fma(wd[0], b, q0);
            q1 = __builtin_elementwise_fma(wd[1], b, q1);
            q2 = __builtin_elementwise_fma(wd[2], b, q2);
            q3 = __builtin_elementwise_fma(wd[3], b, q3);
            q0 = __builtin_elementwise_max(q0, zero);
            q1 = __builtin_elementwise_max(q1, zero);
            q2 = __builtin_elementwise_max(q2, zero);
            q3 = __builtin_elementwise_max(q3, zero);
            c0 = __builtin_amdgcn_fdot2(q0, v, c0, false);
            c1 = __builtin_amdgcn_fdot2(q1, v, c1, false);
            c2 = __builtin_amdgcn_fdot2(q2, v, c2, false);
            c3 = __builtin_amdgcn_fdot2(q3, v, c3, false);
        }

        float4 rr;
        rr.x = c0; rr.y = c1; rr.z = c2; rr.w = c3;
        *reinterpret_cast<float4*>(nWr + (size_t)r * DD + col) = rr;
    }
}

extern "C" void kernel_launch(void* const* d_in, const int* in_sizes, int n_in,
                              void* d_out, int out_size, void* d_ws, size_t ws_size,
                              hipStream_t stream) {
    const float* x   = (const float*)d_in[0];
    const float* W1  = (const float*)d_in[1];
    const float* b1  = (const float*)d_in[2];
    const float* W2  = (const float*)d_in[3];
    const float* b2  = (const float*)d_in[4];
    const float* W3  = (const float*)d_in[5];
    const float* b3  = (const float*)d_in[6];
    const float* Wm1 = (const float*)d_in[7];
    const float* bm1 = (const float*)d_in[8];
    const float* Wm2 = (const float*)d_in[9];
    const float* bm2 = (const float*)d_in[10];

    float* out = (float*)d_out;            // out: [2048]
    float* nW  = out + DD;                 // nW1|nW2|nW3: 3 x 2048 x 2048
    float* a1  = (float*)d_ws;             // [2048]
    float* a2  = a1 + DD;                  // [2048]
    unsigned* cst = (unsigned*)(a2 + DD);  // [80] packed f16x2 constants

    gemv_relu_prep_k<<<DD / 4 + 1, 256, 0, stream>>>(W1, x, b1, a1, Wm1, bm1, Wm2, cst);
    gemv_relu_k<<<DD / 4, 256, 0, stream>>>(W2, a1, b2, a2);
    gemv_relu_k<<<DD / 4, 256, 0, stream>>>(W3, a2, b3, out);
    meta_k<<<3 * DD / 8, 512, 0, stream>>>(W1, W2, W3, x, a1, a2, out,
                                           cst, bm2, nW);
}